// Round 6
// baseline (459.073 us; speedup 1.0000x reference)
//
#include <hip/hip_runtime.h>
#include <stdint.h>

typedef unsigned short u16;
using bf16x8 = __attribute__((ext_vector_type(8))) __bf16;
using f32x4  = __attribute__((ext_vector_type(4))) float;

#define MFMA16(a,b,c) __builtin_amdgcn_mfma_f32_16x16x32_bf16((a),(b),(c),0,0,0)

__device__ __forceinline__ u16 f2bf(float f) {
  union { float f; uint32_t u; } v; v.f = f;
  uint32_t r = v.u + 0x7FFFu + ((v.u >> 16) & 1u);
  return (u16)(r >> 16);
}

// async global->LDS, 16B per lane; lds ptr must be wave-uniform (HW: base + lane*16)
__device__ __forceinline__ void gload_lds16(const void* g, void* l) {
  typedef const __attribute__((address_space(1))) void* gp_t;
  typedef __attribute__((address_space(3))) void* lp_t;
  __builtin_amdgcn_global_load_lds((gp_t)(uintptr_t)g,
                                   (lp_t)(uint32_t)(uintptr_t)l, 16, 0, 0);
}

// ---------------- adaLN stage 1 ----------------
__global__ __launch_bounds__(256)
void adaln_part_k(const float* __restrict__ c, const float* __restrict__ w,
                  float* __restrict__ partial) {
  const int jb = blockIdx.x, ks = blockIdx.y;
  const int j = jb * 256 + threadIdx.x;
  __shared__ float sil[8][32];
  {
    int b = threadIdx.x >> 5, kk = threadIdx.x & 31;
    float v = c[b * 1024 + ks * 32 + kk];
    sil[b][kk] = v / (1.f + __expf(-v));
  }
  __syncthreads();
  float acc[8] = {0,0,0,0,0,0,0,0};
#pragma unroll 8
  for (int kk = 0; kk < 32; ++kk) {
    float wv = w[(size_t)(ks * 32 + kk) * 6144 + j];
#pragma unroll
    for (int b = 0; b < 8; ++b) acc[b] += sil[b][kk] * wv;
  }
#pragma unroll
  for (int b = 0; b < 8; ++b)
    partial[((size_t)ks * 8 + b) * 6144 + j] = acc[b];
}

// ---------------- adaLN stage 2 ----------------
__global__ __launch_bounds__(256)
void adaln_red_k(const float* __restrict__ partial, const float* __restrict__ bias,
                 float* __restrict__ cmod) {
  int g = blockIdx.x * 256 + threadIdx.x;
  int j = g % 6144;
  float s = bias[j];
#pragma unroll 8
  for (int ks = 0; ks < 32; ++ks)
    s += partial[(size_t)ks * 8 * 6144 + g];
  cmod[g] = s;
}

// ------- weight cast+transpose: fp32 [K][N] -> bf16 [N][K]; cols [lo,hi) scaled -------
__global__ __launch_bounds__(256)
void tcast_k(const float* __restrict__ in, u16* __restrict__ out, int K, int N,
             int lo, int hi, float scale) {
  __shared__ u16 t[64][65];
  int n0 = blockIdx.x * 64, k0 = blockIdx.y * 64;
#pragma unroll
  for (int i = 0; i < 16; ++i) {
    int idx = i * 256 + threadIdx.x;
    int r = idx >> 6, cc = idx & 63;
    float v = in[(size_t)(k0 + r) * N + n0 + cc];
    int n = n0 + cc;
    if (n >= lo && n < hi) v *= scale;
    t[r][cc] = f2bf(v);
  }
  __syncthreads();
#pragma unroll
  for (int i = 0; i < 16; ++i) {
    int idx = i * 256 + threadIdx.x;
    int r = idx >> 6, cc = idx & 63;
    out[(size_t)(n0 + r) * K + k0 + cc] = t[cc][r];
  }
}

// ---------------- LN + modulate -> bf16 ----------------
__global__ __launch_bounds__(256)
void lnmod_k(const float* __restrict__ x, const float* __restrict__ cmod,
             int shift_off, int scale_off, u16* __restrict__ out) {
  int row = blockIdx.x;
  int b = row >> 10;
  const float4* xr = (const float4*)(x + (size_t)row * 1024);
  float4 v = xr[threadIdx.x];
  float s = v.x + v.y + v.z + v.w;
  float sq = v.x * v.x + v.y * v.y + v.z * v.z + v.w * v.w;
#pragma unroll
  for (int m = 32; m >= 1; m >>= 1) {
    s  += __shfl_xor(s, m);
    sq += __shfl_xor(sq, m);
  }
  __shared__ float ss[4], ssq[4];
  int wave = threadIdx.x >> 6, lane = threadIdx.x & 63;
  if (lane == 0) { ss[wave] = s; ssq[wave] = sq; }
  __syncthreads();
  s  = ss[0] + ss[1] + ss[2] + ss[3];
  sq = ssq[0] + ssq[1] + ssq[2] + ssq[3];
  float mean = s * (1.f / 1024.f);
  float var  = sq * (1.f / 1024.f) - mean * mean;
  float rstd = rsqrtf(var + 1e-6f);
  int col = threadIdx.x * 4;
  const float* sh = cmod + (size_t)b * 6144 + shift_off + col;
  const float* sc = cmod + (size_t)b * 6144 + scale_off + col;
  float xv[4] = {v.x, v.y, v.z, v.w};
  union { u16 o[4]; uint64_t u; } pk;
#pragma unroll
  for (int j = 0; j < 4; ++j)
    pk.o[j] = f2bf((xv[j] - mean) * rstd * (1.f + sc[j]) + sh[j]);
  *(uint64_t*)(out + (size_t)row * 1024 + col) = pk.u;
}

// ---------------- transpose V section of qkv -> vt[b,h,ch,s] bf16 ----------------
__global__ __launch_bounds__(256)
void tv_k(const u16* __restrict__ qkv, u16* __restrict__ vt) {
  __shared__ u16 t[64][65];
  int r0 = blockIdx.x * 64;
  int h = blockIdx.y;
  int b = r0 >> 10;
  int s0 = r0 & 1023;
#pragma unroll
  for (int i = 0; i < 16; ++i) {
    int idx = i * 256 + threadIdx.x;
    int r = idx >> 6, cc = idx & 63;
    t[r][cc] = qkv[(size_t)(r0 + r) * 3072 + 2048 + h * 64 + cc];
  }
  __syncthreads();
#pragma unroll
  for (int i = 0; i < 16; ++i) {
    int idx = i * 256 + threadIdx.x;
    int ch = idx >> 6, scc = idx & 63;
    vt[((size_t)(b * 16 + h) * 64 + ch) * 1024 + s0 + scc] = t[scc][ch];
  }
}

// ======== GEMM v4: faithful m201-style 256x256 8-phase, 2 LDS buffers, counted vmcnt ========
// BM=BN=256 BK=64, 512 thr = 8 waves (2M x 4N), wave tile 128x64, acc[8][4] f32x4.
// LDS: 2 buffers x (A 256x64 + B 256x64) bf16 = 128 KiB. Rows 128B, (r&7) 16B-chunk XOR
// swizzle (inverse-swizzled global source; swizzled ds_read).
// Per K-tile kt (buf cur=kt&1), 4 phases; each phase {reads/stage issue; s_barrier;
// setprio(1) 16 MFMA setprio(0); s_barrier}:
//   ph(0,0): read A[mh0] 8x b128 + B[nh0] 4x          -> MFMA m0-3 x n0-1
//   ph(0,1): read B[nh1] 4x                           -> MFMA m0-3 x n2-3
//   ph(1,0): read A[mh1] 8x; stage B halves of kt+2   -> MFMA m4-7 x n0-1
//   ph(1,1): stage A halves of kt+2                   -> MFMA m4-7 x n2-3; vmcnt(8); bar
// Race-freedom: B slots of buf[cur] last read in ph(0,1) (barrier-separated from ph(1,0)
// stage issue); A slots last read in ph(1,0); async LDS writes land only after issue.
// vmcnt(8) leaves kt+2's 8 loads in flight across the K-tile boundary (never 0 in steady).
__device__ __forceinline__ float gelu_f(float x) {
  float z = 1.5957691216057308f * (x + 0.044715f * x * x * x);
  return x / (1.f + __expf(-z));
}

template <int EP>
__global__ __launch_bounds__(512, 2)
void gemm8_k(const u16* __restrict__ A, const u16* __restrict__ Bt,
             int N, int K,
             const float* __restrict__ bias, const float* __restrict__ resid,
             const float* __restrict__ gate, void* __restrict__ outp) {
  __shared__ __align__(16) u16 As[2][256 * 64];
  __shared__ __align__(16) u16 Bs[2][256 * 64];
  const int bn = blockIdx.x, bm = blockIdx.y;
  const int tid = threadIdx.x;
  const int wave = tid >> 6, lane = tid & 63;
  const int l15 = lane & 15, lhi = lane >> 4;
  const int wm = wave >> 2, wn = wave & 3;       // 2(M) x 4(N)
  const int nkt = K >> 6;
  const size_t arow0 = (size_t)bm * 256;
  const size_t brow0 = (size_t)bn * 256;

  f32x4 acc[8][4] = {};

  // stage one 128-row half (16 KB) of A or B for K-tile kt into buf: 2 gloads/thread
  auto stage_half = [&](const u16* mat, size_t row0, u16* dst, int kt) {
    const u16* src = mat + row0 * K + (size_t)kt * 64;
#pragma unroll
    for (int i = 0; i < 2; ++i) {
      int q = i * 512 + tid;
      int r = q >> 3, cc = (q & 7) ^ (r & 7);
      gload_lds16(src + (size_t)r * K + cc * 8, dst + (i * 8 + wave) * 512);
    }
  };
  auto lda = [&](int cur, int row, int kh) -> bf16x8 {
    int cc = (kh * 4 + lhi) ^ (row & 7);
    return *(const bf16x8*)&As[cur][row * 64 + cc * 8];
  };
  auto ldb = [&](int cur, int row, int kh) -> bf16x8 {
    int cc = (kh * 4 + lhi) ^ (row & 7);
    return *(const bf16x8*)&Bs[cur][row * 64 + cc * 8];
  };

  // prologue: stage K-tiles 0 and 1 (8 loads each); wait for kt0 only
  stage_half(A, arow0,       &As[0][0],        0);
  stage_half(A, arow0 + 128, &As[0][128 * 64], 0);
  stage_half(Bt, brow0,       &Bs[0][0],        0);
  stage_half(Bt, brow0 + 128, &Bs[0][128 * 64], 0);
  stage_half(A, arow0,       &As[1][0],        1);
  stage_half(A, arow0 + 128, &As[1][128 * 64], 1);
  stage_half(Bt, brow0,       &Bs[1][0],        1);
  stage_half(Bt, brow0 + 128, &Bs[1][128 * 64], 1);
  asm volatile("s_waitcnt vmcnt(8)" ::: "memory");
  __builtin_amdgcn_s_barrier();

  bf16x8 afr[4][2], bfr[4][2];
  for (int kt = 0; kt < nkt; ++kt) {
    const int cur = kt & 1;
    const bool pf = (kt + 2 < nkt);

    // ---- phase (0,0): A mh0 (8 reads) + B nh0 (4 reads); MFMA m0-3 x n0-1 ----
#pragma unroll
    for (int m = 0; m < 4; ++m) {
      int r = wm * 128 + m * 16 + l15;
      afr[m][0] = lda(cur, r, 0); afr[m][1] = lda(cur, r, 1);
    }
#pragma unroll
    for (int n = 0; n < 2; ++n) {
      int r = wn * 64 + n * 16 + l15;
      bfr[n][0] = ldb(cur, r, 0); bfr[n][1] = ldb(cur, r, 1);
    }
    __builtin_amdgcn_s_barrier();
    __builtin_amdgcn_s_setprio(1);
#pragma unroll
    for (int m = 0; m < 4; ++m)
#pragma unroll
      for (int n = 0; n < 2; ++n) {
        acc[m][n] = MFMA16(afr[m][0], bfr[n][0], acc[m][n]);
        acc[m][n] = MFMA16(afr[m][1], bfr[n][1], acc[m][n]);
      }
    __builtin_amdgcn_s_setprio(0);
    __builtin_amdgcn_s_barrier();

    // ---- phase (0,1): B nh1 (4 reads); MFMA m0-3 x n2-3 ----
#pragma unroll
    for (int n = 2; n < 4; ++n) {
      int r = wn * 64 + n * 16 + l15;
      bfr[n][0] = ldb(cur, r, 0); bfr[n][1] = ldb(cur, r, 1);
    }
    __builtin_amdgcn_s_barrier();
    __builtin_amdgcn_s_setprio(1);
#pragma unroll
    for (int m = 0; m < 4; ++m)
#pragma unroll
      for (int n = 2; n < 4; ++n) {
        acc[m][n] = MFMA16(afr[m][0], bfr[n][0], acc[m][n]);
        acc[m][n] = MFMA16(afr[m][1], bfr[n][1], acc[m][n]);
      }
    __builtin_amdgcn_s_setprio(0);
    __builtin_amdgcn_s_barrier();

    // ---- phase (1,0): A mh1 (8 reads); stage B halves of kt+2; MFMA m4-7 x n0-1 ----
#pragma unroll
    for (int m = 0; m < 4; ++m) {
      int r = wm * 128 + 64 + m * 16 + l15;
      afr[m][0] = lda(cur, r, 0); afr[m][1] = lda(cur, r, 1);
    }
    if (pf) {
      stage_half(Bt, brow0,       &Bs[cur][0],        kt + 2);
      stage_half(Bt, brow0 + 128, &Bs[cur][128 * 64], kt + 2);
    }
    __builtin_amdgcn_s_barrier();
    __builtin_amdgcn_s_setprio(1);
#pragma unroll
    for (int m = 0; m < 4; ++m)
#pragma unroll
      for (int n = 0; n < 2; ++n) {
        acc[m + 4][n] = MFMA16(afr[m][0], bfr[n][0], acc[m + 4][n]);
        acc[m + 4][n] = MFMA16(afr[m][1], bfr[n][1], acc[m + 4][n]);
      }
    __builtin_amdgcn_s_setprio(0);
    __builtin_amdgcn_s_barrier();

    // ---- phase (1,1): stage A halves of kt+2; MFMA m4-7 x n2-3; K-tile checkpoint ----
    if (pf) {
      stage_half(A, arow0,       &As[cur][0],        kt + 2);
      stage_half(A, arow0 + 128, &As[cur][128 * 64], kt + 2);
    }
    __builtin_amdgcn_s_barrier();
    __builtin_amdgcn_s_setprio(1);
#pragma unroll
    for (int m = 0; m < 4; ++m)
#pragma unroll
      for (int n = 2; n < 4; ++n) {
        acc[m + 4][n] = MFMA16(afr[m][0], bfr[n][0], acc[m + 4][n]);
        acc[m + 4][n] = MFMA16(afr[m][1], bfr[n][1], acc[m + 4][n]);
      }
    __builtin_amdgcn_s_setprio(0);
    if (kt + 1 < nkt) {
      if (pf) asm volatile("s_waitcnt vmcnt(8)" ::: "memory");
      else    asm volatile("s_waitcnt vmcnt(0)" ::: "memory");
      __builtin_amdgcn_s_barrier();
    }
  }

  // epilogue
#pragma unroll
  for (int m = 0; m < 8; ++m) {
    int row = bm * 256 + wm * 128 + m * 16 + lhi * 4;
#pragma unroll
    for (int n = 0; n < 4; ++n) {
      int col = bn * 256 + wn * 64 + n * 16 + l15;
#pragma unroll
      for (int r = 0; r < 4; ++r) {
        int rr = row + r;
        float v = acc[m][n][r];
        if (EP == 0) {
          ((u16*)outp)[(size_t)rr * N + col] = f2bf(v);
        } else if (EP == 1) {
          ((u16*)outp)[(size_t)rr * N + col] = f2bf(gelu_f(v + bias[col]));
        } else {
          float t2 = v + bias[col];
          int b = rr >> 10;
          float res = resid[(size_t)rr * N + col];
          ((float*)outp)[(size_t)rr * N + col] = res + gate[(size_t)b * 6144 + col] * t2;
        }
      }
    }
  }
}

// ---------------- flash attention: block = (q-tile 64, head, batch) ----------------
__global__ __launch_bounds__(256)
void attn_k(const u16* __restrict__ qkv, const u16* __restrict__ vt,
            u16* __restrict__ y) {
  const int qt = blockIdx.x, h = blockIdx.y, b = blockIdx.z;
  const int tid = threadIdx.x, wave = tid >> 6, lane = tid & 63;
  const int l15 = lane & 15, lhi = lane >> 4;
  __shared__ __align__(16) u16 Qs[64 * 64];
  __shared__ __align__(16) u16 Ks[2][64 * 64];
  __shared__ __align__(16) u16 Vs[2][64 * 64];
  __shared__ __align__(16) u16 Ps[64 * 64];
  const size_t qrow0 = (size_t)b * 1024 + qt * 64;
  const size_t krow0 = (size_t)b * 1024;
  const size_t vrow0 = (size_t)(b * 16 + h) * 64;

  auto stageQ = [&]() {
#pragma unroll
    for (int i = 0; i < 2; ++i) {
      int c = (i * 4 + wave) * 64 + lane;
      int r = c >> 3, j = (c & 7) ^ (c >> 3 & 7);
      gload_lds16(qkv + (qrow0 + r) * 3072 + 1024 + h * 64 + j * 8,
                  &Qs[(i * 4 + wave) * 512]);
    }
  };
  auto stageKV = [&](int buf, int kt) {
#pragma unroll
    for (int i = 0; i < 2; ++i) {
      int c = (i * 4 + wave) * 64 + lane;
      int r = c >> 3, j = (c & 7) ^ (c >> 3 & 7);
      gload_lds16(qkv + (krow0 + kt * 64 + r) * 3072 + h * 64 + j * 8,
                  &Ks[buf][(i * 4 + wave) * 512]);
      gload_lds16(vt + (vrow0 + r) * 1024 + kt * 64 + j * 8,
                  &Vs[buf][(i * 4 + wave) * 512]);
    }
  };
  auto ldb = [](const u16* base, int row, int cc) -> bf16x8 {
    return *(const bf16x8*)&base[row * 64 + ((cc ^ (row & 7)) << 3)];
  };

  stageQ();
  stageKV(0, 0);
  __syncthreads();
  bf16x8 qf[2];
  qf[0] = ldb(Qs, wave * 16 + l15, lhi);
  qf[1] = ldb(Qs, wave * 16 + l15, 4 + lhi);

  bf16x8 ones;
#pragma unroll
  for (int j = 0; j < 8; ++j) ones[j] = (__bf16)1.0f;

  float m_r[4];
  f32x4 o[5] = {};
#pragma unroll
  for (int r = 0; r < 4; ++r) m_r[r] = -3.0e38f;

  for (int kt = 0; kt < 16; ++kt) {
    int cur = kt & 1;
    if (kt < 15) stageKV(cur ^ 1, kt + 1);
    f32x4 sf[4] = {};
    __builtin_amdgcn_s_setprio(1);
#pragma unroll
    for (int n = 0; n < 4; ++n) {
      bf16x8 k0 = ldb(Ks[cur], n * 16 + l15, lhi);
      bf16x8 k1 = ldb(Ks[cur], n * 16 + l15, 4 + lhi);
      sf[n] = MFMA16(qf[0], k0, sf[n]);
      sf[n] = MFMA16(qf[1], k1, sf[n]);
    }
    __builtin_amdgcn_s_setprio(0);
#pragma unroll
    for (int r = 0; r < 4; ++r) {
      float mx = fmaxf(fmaxf(sf[0][r], sf[1][r]), fmaxf(sf[2][r], sf[3][r]));
      mx = fmaxf(mx, __shfl_xor(mx, 1));
      mx = fmaxf(mx, __shfl_xor(mx, 2));
      mx = fmaxf(mx, __shfl_xor(mx, 4));
      mx = fmaxf(mx, __shfl_xor(mx, 8));
      float mn = fmaxf(m_r[r], mx);
      float al = __expf(m_r[r] - mn);
      m_r[r] = mn;
      float p0 = __expf(sf[0][r] - mn);
      float p1 = __expf(sf[1][r] - mn);
      float p2 = __expf(sf[2][r] - mn);
      float p3 = __expf(sf[3][r] - mn);
      o[0][r] *= al; o[1][r] *= al; o[2][r] *= al; o[3][r] *= al; o[4][r] *= al;
      int row = wave * 16 + lhi * 4 + r;
      int rb = row * 64, sw = (row & 7) << 3;
      Ps[rb + (l15 ^ sw)]        = f2bf(p0);
      Ps[rb + ((l15 + 16) ^ sw)] = f2bf(p1);
      Ps[rb + ((l15 + 32) ^ sw)] = f2bf(p2);
      Ps[rb + ((l15 + 48) ^ sw)] = f2bf(p3);
    }
    bf16x8 pf0 = ldb(Ps, wave * 16 + l15, lhi);
    bf16x8 pf1 = ldb(Ps, wave * 16 + l15, 4 + lhi);
    __builtin_amdgcn_s_setprio(1);
#pragma unroll
    for (int n = 0; n < 4; ++n) {
      bf16x8 v0 = ldb(Vs[cur], n * 16 + l15, lhi);
      bf16x8 v1 = ldb(Vs[cur], n * 16 + l15, 4 + lhi);
      o[n] = MFMA16(pf0, v0, o[n]);
      o[n] = MFMA16(pf1, v1, o[n]);
    }
    o[4] = MFMA16(pf0, ones, o[4]);
    o[4] = MFMA16(pf1, ones, o[4]);
    __builtin_amdgcn_s_setprio(0);
    __syncthreads();
  }
#pragma unroll
  for (int r = 0; r < 4; ++r) {
    float inv = 1.0f / o[4][r];
    size_t yrow = (qrow0 + wave * 16 + lhi * 4 + r) * 1024 + h * 64 + l15;
    y[yrow]      = f2bf(o[0][r] * inv);
    y[yrow + 16] = f2bf(o[1][r] * inv);
    y[yrow + 32] = f2bf(o[2][r] * inv);
    y[yrow + 48] = f2bf(o[3][r] * inv);
  }
}

// ---------------- host ----------------
extern "C" void kernel_launch(void* const* d_in, const int* in_sizes, int n_in,
                              void* d_out, int out_size, void* d_ws, size_t ws_size,
                              hipStream_t stream) {
  const float* x      = (const float*)d_in[0];
  const float* c      = (const float*)d_in[1];
  const float* w_ada  = (const float*)d_in[2];
  const float* b_ada  = (const float*)d_in[3];
  const float* w_qkv  = (const float*)d_in[4];
  const float* w_proj = (const float*)d_in[5];
  const float* b_proj = (const float*)d_in[6];
  const float* w_mlp1 = (const float*)d_in[7];
  const float* b_mlp1 = (const float*)d_in[8];
  const float* w_mlp2 = (const float*)d_in[9];
  const float* b_mlp2 = (const float*)d_in[10];
  float* out = (float*)d_out;

  char* ws = (char*)d_ws;
  size_t off = 0;
  auto alloc = [&](size_t bytes) {
    void* p = ws + off;
    off += (bytes + 255) & ~(size_t)255;
    return p;
  };
  float* cmod  = (float*)alloc((size_t)8 * 6144 * 4);
  float* apart = (float*)alloc((size_t)32 * 8 * 6144 * 4);
  u16* wqkvT   = (u16*)alloc((size_t)3072 * 1024 * 2);
  u16* wprojT  = (u16*)alloc((size_t)1024 * 1024 * 2);
  u16* wmlp1T  = (u16*)alloc((size_t)4096 * 1024 * 2);
  u16* wmlp2T  = (u16*)alloc((size_t)1024 * 4096 * 2);
  u16* xmod    = (u16*)alloc((size_t)8192 * 1024 * 2);   // reused as attention out y
  u16* qkv     = (u16*)alloc((size_t)8192 * 3072 * 2);   // front reused as x_mod2
  u16* vt      = (u16*)alloc((size_t)8 * 16 * 64 * 1024 * 2);
  float* x1    = (float*)alloc((size_t)8192 * 1024 * 4);
  u16* hbuf    = (u16*)alloc((size_t)8192 * 4096 * 2);
  u16* ybuf  = xmod;   // x_mod dead after qkv GEMM
  u16* xmod2 = qkv;    // qkv dead after attention

  adaln_part_k<<<dim3(24, 32), 256, 0, stream>>>(c, w_ada, apart);
  adaln_red_k<<<192, 256, 0, stream>>>(apart, b_ada, cmod);
  tcast_k<<<dim3(3072 / 64, 1024 / 64), 256, 0, stream>>>(w_qkv,  wqkvT,  1024, 3072,
                                                          1024, 2048, 1.0f / 64.0f);
  tcast_k<<<dim3(1024 / 64, 1024 / 64), 256, 0, stream>>>(w_proj, wprojT, 1024, 1024, 0, 0, 1.f);
  tcast_k<<<dim3(4096 / 64, 1024 / 64), 256, 0, stream>>>(w_mlp1, wmlp1T, 1024, 4096, 0, 0, 1.f);
  tcast_k<<<dim3(1024 / 64, 4096 / 64), 256, 0, stream>>>(w_mlp2, wmlp2T, 4096, 1024, 0, 0, 1.f);
  lnmod_k<<<8192, 256, 0, stream>>>(x, cmod, 0, 1024, xmod);
  gemm8_k<0><<<dim3(3072 / 256, 8192 / 256), 512, 0, stream>>>(
      xmod, wqkvT, 3072, 1024, nullptr, nullptr, nullptr, qkv);
  tv_k<<<dim3(128, 16), 256, 0, stream>>>(qkv, vt);
  attn_k<<<dim3(16, 16, 8), 256, 0, stream>>>(qkv, vt, ybuf);
  gemm8_k<2><<<dim3(1024 / 256, 8192 / 256), 512, 0, stream>>>(
      ybuf, wprojT, 1024, 1024, b_proj, x, cmod + 2048, x1);
  lnmod_k<<<8192, 256, 0, stream>>>(x1, cmod, 3072, 4096, xmod2);
  gemm8_k<1><<<dim3(4096 / 256, 8192 / 256), 512, 0, stream>>>(
      xmod2, wmlp1T, 4096, 1024, b_mlp1, nullptr, nullptr, hbuf);
  gemm8_k<2><<<dim3(1024 / 256, 8192 / 256), 512, 0, stream>>>(
      hbuf, wmlp2T, 1024, 4096, b_mlp2, x1, cmod + 5120, out);
}

// Round 7
// 437.106 us; speedup vs baseline: 1.0503x; 1.0503x over previous
//
#include <hip/hip_runtime.h>
#include <stdint.h>

typedef unsigned short u16;
using bf16x8 = __attribute__((ext_vector_type(8))) __bf16;
using f32x4  = __attribute__((ext_vector_type(4))) float;

#define MFMA16(a,b,c) __builtin_amdgcn_mfma_f32_16x16x32_bf16((a),(b),(c),0,0,0)

__device__ __forceinline__ u16 f2bf(float f) {
  union { float f; uint32_t u; } v; v.f = f;
  uint32_t r = v.u + 0x7FFFu + ((v.u >> 16) & 1u);
  return (u16)(r >> 16);
}

// async global->LDS, 16B per lane; lds ptr must be wave-uniform (HW: base + lane*16)
__device__ __forceinline__ void gload_lds16(const void* g, void* l) {
  typedef const __attribute__((address_space(1))) void* gp_t;
  typedef __attribute__((address_space(3))) void* lp_t;
  __builtin_amdgcn_global_load_lds((gp_t)(uintptr_t)g,
                                   (lp_t)(uint32_t)(uintptr_t)l, 16, 0, 0);
}

// ---------------- adaLN stage 1 ----------------
__global__ __launch_bounds__(256)
void adaln_part_k(const float* __restrict__ c, const float* __restrict__ w,
                  float* __restrict__ partial) {
  const int jb = blockIdx.x, ks = blockIdx.y;
  const int j = jb * 256 + threadIdx.x;
  __shared__ float sil[8][32];
  {
    int b = threadIdx.x >> 5, kk = threadIdx.x & 31;
    float v = c[b * 1024 + ks * 32 + kk];
    sil[b][kk] = v / (1.f + __expf(-v));
  }
  __syncthreads();
  float acc[8] = {0,0,0,0,0,0,0,0};
#pragma unroll 8
  for (int kk = 0; kk < 32; ++kk) {
    float wv = w[(size_t)(ks * 32 + kk) * 6144 + j];
#pragma unroll
    for (int b = 0; b < 8; ++b) acc[b] += sil[b][kk] * wv;
  }
#pragma unroll
  for (int b = 0; b < 8; ++b)
    partial[((size_t)ks * 8 + b) * 6144 + j] = acc[b];
}

// ---------------- adaLN stage 2 ----------------
__global__ __launch_bounds__(256)
void adaln_red_k(const float* __restrict__ partial, const float* __restrict__ bias,
                 float* __restrict__ cmod) {
  int g = blockIdx.x * 256 + threadIdx.x;
  int j = g % 6144;
  float s = bias[j];
#pragma unroll 8
  for (int ks = 0; ks < 32; ++ks)
    s += partial[(size_t)ks * 8 * 6144 + g];
  cmod[g] = s;
}

// ------- weight cast+transpose: fp32 [K][N] -> bf16 [N][K]; cols [lo,hi) scaled -------
__global__ __launch_bounds__(256)
void tcast_k(const float* __restrict__ in, u16* __restrict__ out, int K, int N,
             int lo, int hi, float scale) {
  __shared__ u16 t[64][65];
  int n0 = blockIdx.x * 64, k0 = blockIdx.y * 64;
#pragma unroll
  for (int i = 0; i < 16; ++i) {
    int idx = i * 256 + threadIdx.x;
    int r = idx >> 6, cc = idx & 63;
    float v = in[(size_t)(k0 + r) * N + n0 + cc];
    int n = n0 + cc;
    if (n >= lo && n < hi) v *= scale;
    t[r][cc] = f2bf(v);
  }
  __syncthreads();
#pragma unroll
  for (int i = 0; i < 16; ++i) {
    int idx = i * 256 + threadIdx.x;
    int r = idx >> 6, cc = idx & 63;
    out[(size_t)(n0 + r) * K + k0 + cc] = t[cc][r];
  }
}

// ---------------- LN + modulate -> bf16 ----------------
__global__ __launch_bounds__(256)
void lnmod_k(const float* __restrict__ x, const float* __restrict__ cmod,
             int shift_off, int scale_off, u16* __restrict__ out) {
  int row = blockIdx.x;
  int b = row >> 10;
  const float4* xr = (const float4*)(x + (size_t)row * 1024);
  float4 v = xr[threadIdx.x];
  float s = v.x + v.y + v.z + v.w;
  float sq = v.x * v.x + v.y * v.y + v.z * v.z + v.w * v.w;
#pragma unroll
  for (int m = 32; m >= 1; m >>= 1) {
    s  += __shfl_xor(s, m);
    sq += __shfl_xor(sq, m);
  }
  __shared__ float ss[4], ssq[4];
  int wave = threadIdx.x >> 6, lane = threadIdx.x & 63;
  if (lane == 0) { ss[wave] = s; ssq[wave] = sq; }
  __syncthreads();
  s  = ss[0] + ss[1] + ss[2] + ss[3];
  sq = ssq[0] + ssq[1] + ssq[2] + ssq[3];
  float mean = s * (1.f / 1024.f);
  float var  = sq * (1.f / 1024.f) - mean * mean;
  float rstd = rsqrtf(var + 1e-6f);
  int col = threadIdx.x * 4;
  const float* sh = cmod + (size_t)b * 6144 + shift_off + col;
  const float* sc = cmod + (size_t)b * 6144 + scale_off + col;
  float xv[4] = {v.x, v.y, v.z, v.w};
  union { u16 o[4]; uint64_t u; } pk;
#pragma unroll
  for (int j = 0; j < 4; ++j)
    pk.o[j] = f2bf((xv[j] - mean) * rstd * (1.f + sc[j]) + sh[j]);
  *(uint64_t*)(out + (size_t)row * 1024 + col) = pk.u;
}

// ---------------- transpose V section of qkv -> vt[b,h,ch,s] bf16 ----------------
__global__ __launch_bounds__(256)
void tv_k(const u16* __restrict__ qkv, u16* __restrict__ vt) {
  __shared__ u16 t[64][65];
  int r0 = blockIdx.x * 64;
  int h = blockIdx.y;
  int b = r0 >> 10;
  int s0 = r0 & 1023;
#pragma unroll
  for (int i = 0; i < 16; ++i) {
    int idx = i * 256 + threadIdx.x;
    int r = idx >> 6, cc = idx & 63;
    t[r][cc] = qkv[(size_t)(r0 + r) * 3072 + 2048 + h * 64 + cc];
  }
  __syncthreads();
#pragma unroll
  for (int i = 0; i < 16; ++i) {
    int idx = i * 256 + threadIdx.x;
    int ch = idx >> 6, scc = idx & 63;
    vt[((size_t)(b * 16 + h) * 64 + ch) * 1024 + s0 + scc] = t[scc][ch];
  }
}

// ==== GEMM v5: 256x256 4-phase with FRAGMENT READ-AHEAD (reads issue one phase before
// consumption -> LDS pipe drains under the MFMA cluster), 2 LDS buffers, counted vmcnt,
// XCD-aware bijective block swizzle. ====
// BM=BN=256 BK=64, 512 thr = 8 waves (2M x 4N), wave tile 128x64, acc[8][4] f32x4.
// Frag sets: A1/A2 (mh0/mh1) 32 VGPR each, B1/B2 (nh0/nh1) 16 each.
// Per K-tile kt (c=kt&1, o=c^1):
//  ph0: bar; read B-nh1(c)->B2;                         MFMA A1xB1 (m0-3,n0-1)
//  ph1: bar; stage B(kt+2)->Bs[c]; read A-mh1(c)->A2;   MFMA A1xB2 (m0-3,n2-3)
//  ph2: bar; vmcnt(4); stage A(kt+2)->As[c]; read A-mh0(o)->A1;  MFMA A2xB1 (m4-7,n0-1)
//  ph3: bar; read B-nh0(o)->B1;                         MFMA A2xB2 (m4-7,n2-3)
// vmcnt(4) waits kt+1's 8 loads (issued in kt-1) leaving kt+2's B-4 in flight; it sits
// before the first read of buf o. Slot-reuse: stage B(c) after last B(c) read (ph0),
// stage A(c) after last A(c) read (ph1), barrier-separated.
__device__ __forceinline__ float gelu_f(float x) {
  float z = 1.5957691216057308f * (x + 0.044715f * x * x * x);
  return x / (1.f + __expf(-z));
}

template <int EP>
__global__ __launch_bounds__(512, 2)
void gemm8_k(const u16* __restrict__ A, const u16* __restrict__ Bt,
             int N, int K,
             const float* __restrict__ bias, const float* __restrict__ resid,
             const float* __restrict__ gate, void* __restrict__ outp) {
  __shared__ __align__(16) u16 As[2][256 * 64];
  __shared__ __align__(16) u16 Bs[2][256 * 64];
  // XCD-aware bijective swizzle (all grids have nwg % 8 == 0)
  const int nwg = gridDim.x * gridDim.y;
  int bid = blockIdx.y * gridDim.x + blockIdx.x;
  int swz = (bid & 7) * (nwg >> 3) + (bid >> 3);
  const int bn = swz % gridDim.x, bm = swz / gridDim.x;
  const int tid = threadIdx.x;
  const int wave = tid >> 6, lane = tid & 63;
  const int l15 = lane & 15, lhi = lane >> 4;
  const int wm = wave >> 2, wn = wave & 3;       // 2(M) x 4(N)
  const int nkt = K >> 6;
  const size_t arow0 = (size_t)bm * 256;
  const size_t brow0 = (size_t)bn * 256;

  f32x4 acc[8][4] = {};

  auto stage_half = [&](const u16* mat, size_t row0, u16* dst, int kt) {
    const u16* src = mat + row0 * K + (size_t)kt * 64;
#pragma unroll
    for (int i = 0; i < 2; ++i) {
      int q = i * 512 + tid;
      int r = q >> 3, cc = (q & 7) ^ (r & 7);
      gload_lds16(src + (size_t)r * K + cc * 8, dst + (i * 8 + wave) * 512);
    }
  };
  auto lda = [&](int cur, int row, int kh) -> bf16x8 {
    int cc = (kh * 4 + lhi) ^ (row & 7);
    return *(const bf16x8*)&As[cur][row * 64 + cc * 8];
  };
  auto ldb = [&](int cur, int row, int kh) -> bf16x8 {
    int cc = (kh * 4 + lhi) ^ (row & 7);
    return *(const bf16x8*)&Bs[cur][row * 64 + cc * 8];
  };

  // prologue: stage K-tiles 0 and 1; wait kt0; initial frags (A-mh0, B-nh0 of buf0)
  stage_half(A,  arow0,       &As[0][0],        0);
  stage_half(A,  arow0 + 128, &As[0][128 * 64], 0);
  stage_half(Bt, brow0,       &Bs[0][0],        0);
  stage_half(Bt, brow0 + 128, &Bs[0][128 * 64], 0);
  stage_half(A,  arow0,       &As[1][0],        1);
  stage_half(A,  arow0 + 128, &As[1][128 * 64], 1);
  stage_half(Bt, brow0,       &Bs[1][0],        1);
  stage_half(Bt, brow0 + 128, &Bs[1][128 * 64], 1);
  asm volatile("s_waitcnt vmcnt(8)" ::: "memory");
  __builtin_amdgcn_s_barrier();

  bf16x8 A1[4][2], A2[4][2], B1[2][2], B2[2][2];
#pragma unroll
  for (int m = 0; m < 4; ++m) {
    int r = wm * 128 + m * 16 + l15;
    A1[m][0] = lda(0, r, 0); A1[m][1] = lda(0, r, 1);
  }
#pragma unroll
  for (int n = 0; n < 2; ++n) {
    int r = wn * 64 + n * 16 + l15;
    B1[n][0] = ldb(0, r, 0); B1[n][1] = ldb(0, r, 1);
  }

  for (int kt = 0; kt < nkt; ++kt) {
    const int cur = kt & 1, oth = cur ^ 1;
    const bool nxt = (kt + 1 < nkt), pf2 = (kt + 2 < nkt);

    // ---- ph0: read B-nh1(cur)->B2 ; MFMA A1xB1 ----
    __builtin_amdgcn_s_barrier();
#pragma unroll
    for (int n = 0; n < 2; ++n) {
      int r = wn * 64 + 32 + n * 16 + l15;
      B2[n][0] = ldb(cur, r, 0); B2[n][1] = ldb(cur, r, 1);
    }
    __builtin_amdgcn_s_setprio(1);
#pragma unroll
    for (int m = 0; m < 4; ++m)
#pragma unroll
      for (int n = 0; n < 2; ++n) {
        acc[m][n] = MFMA16(A1[m][0], B1[n][0], acc[m][n]);
        acc[m][n] = MFMA16(A1[m][1], B1[n][1], acc[m][n]);
      }
    __builtin_amdgcn_s_setprio(0);

    // ---- ph1: stage B(kt+2); read A-mh1(cur)->A2 ; MFMA A1xB2 ----
    __builtin_amdgcn_s_barrier();
    if (pf2) {
      stage_half(Bt, brow0,       &Bs[cur][0],        kt + 2);
      stage_half(Bt, brow0 + 128, &Bs[cur][128 * 64], kt + 2);
    }
#pragma unroll
    for (int m = 0; m < 4; ++m) {
      int r = wm * 128 + 64 + m * 16 + l15;
      A2[m][0] = lda(cur, r, 0); A2[m][1] = lda(cur, r, 1);
    }
    __builtin_amdgcn_s_setprio(1);
#pragma unroll
    for (int m = 0; m < 4; ++m)
#pragma unroll
      for (int n = 0; n < 2; ++n) {
        acc[m][n + 2] = MFMA16(A1[m][0], B2[n][0], acc[m][n + 2]);
        acc[m][n + 2] = MFMA16(A1[m][1], B2[n][1], acc[m][n + 2]);
      }
    __builtin_amdgcn_s_setprio(0);

    // ---- ph2: vmcnt; stage A(kt+2); read A-mh0(oth)->A1 ; MFMA A2xB1 ----
    __builtin_amdgcn_s_barrier();
    if (nxt) {
      if (pf2) asm volatile("s_waitcnt vmcnt(4)" ::: "memory");
      else     asm volatile("s_waitcnt vmcnt(0)" ::: "memory");
    }
    if (pf2) {
      stage_half(A, arow0,       &As[cur][0],        kt + 2);
      stage_half(A, arow0 + 128, &As[cur][128 * 64], kt + 2);
    }
    if (nxt) {
#pragma unroll
      for (int m = 0; m < 4; ++m) {
        int r = wm * 128 + m * 16 + l15;
        A1[m][0] = lda(oth, r, 0); A1[m][1] = lda(oth, r, 1);
      }
    }
    __builtin_amdgcn_s_setprio(1);
#pragma unroll
    for (int m = 0; m < 4; ++m)
#pragma unroll
      for (int n = 0; n < 2; ++n) {
        acc[m + 4][n] = MFMA16(A2[m][0], B1[n][0], acc[m + 4][n]);
        acc[m + 4][n] = MFMA16(A2[m][1], B1[n][1], acc[m + 4][n]);
      }
    __builtin_amdgcn_s_setprio(0);

    // ---- ph3: read B-nh0(oth)->B1 ; MFMA A2xB2 ----
    __builtin_amdgcn_s_barrier();
    if (nxt) {
#pragma unroll
      for (int n = 0; n < 2; ++n) {
        int r = wn * 64 + n * 16 + l15;
        B1[n][0] = ldb(oth, r, 0); B1[n][1] = ldb(oth, r, 1);
      }
    }
    __builtin_amdgcn_s_setprio(1);
#pragma unroll
    for (int m = 0; m < 4; ++m)
#pragma unroll
      for (int n = 0; n < 2; ++n) {
        acc[m + 4][n + 2] = MFMA16(A2[m][0], B2[n][0], acc[m + 4][n + 2]);
        acc[m + 4][n + 2] = MFMA16(A2[m][1], B2[n][1], acc[m + 4][n + 2]);
      }
    __builtin_amdgcn_s_setprio(0);
  }

  // epilogue
#pragma unroll
  for (int m = 0; m < 8; ++m) {
    int row = bm * 256 + wm * 128 + m * 16 + lhi * 4;
#pragma unroll
    for (int n = 0; n < 4; ++n) {
      int col = bn * 256 + wn * 64 + n * 16 + l15;
#pragma unroll
      for (int r = 0; r < 4; ++r) {
        int rr = row + r;
        float v = acc[m][n][r];
        if (EP == 0) {
          ((u16*)outp)[(size_t)rr * N + col] = f2bf(v);
        } else if (EP == 1) {
          ((u16*)outp)[(size_t)rr * N + col] = f2bf(gelu_f(v + bias[col]));
        } else {
          float t2 = v + bias[col];
          int b = rr >> 10;
          float res = resid[(size_t)rr * N + col];
          ((float*)outp)[(size_t)rr * N + col] = res + gate[(size_t)b * 6144 + col] * t2;
        }
      }
    }
  }
}

// ---------------- flash attention: block = (q-tile 64, head, batch) ----------------
__global__ __launch_bounds__(256)
void attn_k(const u16* __restrict__ qkv, const u16* __restrict__ vt,
            u16* __restrict__ y) {
  const int qt = blockIdx.x, h = blockIdx.y, b = blockIdx.z;
  const int tid = threadIdx.x, wave = tid >> 6, lane = tid & 63;
  const int l15 = lane & 15, lhi = lane >> 4;
  __shared__ __align__(16) u16 Qs[64 * 64];
  __shared__ __align__(16) u16 Ks[2][64 * 64];
  __shared__ __align__(16) u16 Vs[2][64 * 64];
  __shared__ __align__(16) u16 Ps[64 * 64];
  const size_t qrow0 = (size_t)b * 1024 + qt * 64;
  const size_t krow0 = (size_t)b * 1024;
  const size_t vrow0 = (size_t)(b * 16 + h) * 64;

  auto stageQ = [&]() {
#pragma unroll
    for (int i = 0; i < 2; ++i) {
      int c = (i * 4 + wave) * 64 + lane;
      int r = c >> 3, j = (c & 7) ^ (c >> 3 & 7);
      gload_lds16(qkv + (qrow0 + r) * 3072 + 1024 + h * 64 + j * 8,
                  &Qs[(i * 4 + wave) * 512]);
    }
  };
  auto stageKV = [&](int buf, int kt) {
#pragma unroll
    for (int i = 0; i < 2; ++i) {
      int c = (i * 4 + wave) * 64 + lane;
      int r = c >> 3, j = (c & 7) ^ (c >> 3 & 7);
      gload_lds16(qkv + (krow0 + kt * 64 + r) * 3072 + h * 64 + j * 8,
                  &Ks[buf][(i * 4 + wave) * 512]);
      gload_lds16(vt + (vrow0 + r) * 1024 + kt * 64 + j * 8,
                  &Vs[buf][(i * 4 + wave) * 512]);
    }
  };
  auto ldb = [](const u16* base, int row, int cc) -> bf16x8 {
    return *(const bf16x8*)&base[row * 64 + ((cc ^ (row & 7)) << 3)];
  };

  stageQ();
  stageKV(0, 0);
  __syncthreads();
  bf16x8 qf[2];
  qf[0] = ldb(Qs, wave * 16 + l15, lhi);
  qf[1] = ldb(Qs, wave * 16 + l15, 4 + lhi);

  bf16x8 ones;
#pragma unroll
  for (int j = 0; j < 8; ++j) ones[j] = (__bf16)1.0f;

  float m_r[4];
  f32x4 o[5] = {};
#pragma unroll
  for (int r = 0; r < 4; ++r) m_r[r] = -3.0e38f;

  for (int kt = 0; kt < 16; ++kt) {
    int cur = kt & 1;
    if (kt < 15) stageKV(cur ^ 1, kt + 1);
    f32x4 sf[4] = {};
    __builtin_amdgcn_s_setprio(1);
#pragma unroll
    for (int n = 0; n < 4; ++n) {
      bf16x8 k0 = ldb(Ks[cur], n * 16 + l15, lhi);
      bf16x8 k1 = ldb(Ks[cur], n * 16 + l15, 4 + lhi);
      sf[n] = MFMA16(qf[0], k0, sf[n]);
      sf[n] = MFMA16(qf[1], k1, sf[n]);
    }
    __builtin_amdgcn_s_setprio(0);
#pragma unroll
    for (int r = 0; r < 4; ++r) {
      float mx = fmaxf(fmaxf(sf[0][r], sf[1][r]), fmaxf(sf[2][r], sf[3][r]));
      mx = fmaxf(mx, __shfl_xor(mx, 1));
      mx = fmaxf(mx, __shfl_xor(mx, 2));
      mx = fmaxf(mx, __shfl_xor(mx, 4));
      mx = fmaxf(mx, __shfl_xor(mx, 8));
      float mn = fmaxf(m_r[r], mx);
      float al = __expf(m_r[r] - mn);
      m_r[r] = mn;
      float p0 = __expf(sf[0][r] - mn);
      float p1 = __expf(sf[1][r] - mn);
      float p2 = __expf(sf[2][r] - mn);
      float p3 = __expf(sf[3][r] - mn);
      o[0][r] *= al; o[1][r] *= al; o[2][r] *= al; o[3][r] *= al; o[4][r] *= al;
      int row = wave * 16 + lhi * 4 + r;
      int rb = row * 64, sw = (row & 7) << 3;
      Ps[rb + (l15 ^ sw)]        = f2bf(p0);
      Ps[rb + ((l15 + 16) ^ sw)] = f2bf(p1);
      Ps[rb + ((l15 + 32) ^ sw)] = f2bf(p2);
      Ps[rb + ((l15 + 48) ^ sw)] = f2bf(p3);
    }
    bf16x8 pf0 = ldb(Ps, wave * 16 + l15, lhi);
    bf16x8 pf1 = ldb(Ps, wave * 16 + l15, 4 + lhi);
    __builtin_amdgcn_s_setprio(1);
#pragma unroll
    for (int n = 0; n < 4; ++n) {
      bf16x8 v0 = ldb(Vs[cur], n * 16 + l15, lhi);
      bf16x8 v1 = ldb(Vs[cur], n * 16 + l15, 4 + lhi);
      o[n] = MFMA16(pf0, v0, o[n]);
      o[n] = MFMA16(pf1, v1, o[n]);
    }
    o[4] = MFMA16(pf0, ones, o[4]);
    o[4] = MFMA16(pf1, ones, o[4]);
    __builtin_amdgcn_s_setprio(0);
    __syncthreads();
  }
#pragma unroll
  for (int r = 0; r < 4; ++r) {
    float inv = 1.0f / o[4][r];
    size_t yrow = (qrow0 + wave * 16 + lhi * 4 + r) * 1024 + h * 64 + l15;
    y[yrow]      = f2bf(o[0][r] * inv);
    y[yrow + 16] = f2bf(o[1][r] * inv);
    y[yrow + 32] = f2bf(o[2][r] * inv);
    y[yrow + 48] = f2bf(o[3][r] * inv);
  }
}

// ---------------- host ----------------
extern "C" void kernel_launch(void* const* d_in, const int* in_sizes, int n_in,
                              void* d_out, int out_size, void* d_ws, size_t ws_size,
                              hipStream_t stream) {
  const float* x      = (const float*)d_in[0];
  const float* c      = (const float*)d_in[1];
  const float* w_ada  = (const float*)d_in[2];
  const float* b_ada  = (const float*)d_in[3];
  const float* w_qkv  = (const float*)d_in[4];
  const float* w_proj = (const float*)d_in[5];
  const float* b_proj = (const float*)d_in[6];
  const float* w_mlp1 = (const float*)d_in[7];
  const float* b_mlp1 = (const float*)d_in[8];
  const float* w_mlp2 = (const float*)d_in[9];
  const float* b_mlp2 = (const float*)d_in[10];
  float* out = (float*)d_out;

  char* ws = (char*)d_ws;
  size_t off = 0;
  auto alloc = [&](size_t bytes) {
    void* p = ws + off;
    off += (bytes + 255) & ~(size_t)255;
    return p;
  };
  float* cmod  = (float*)alloc((size_t)8 * 6144 * 4);
  float* apart = (float*)alloc((size_t)32 * 8 * 6144 * 4);
  u16* wqkvT   = (u16*)alloc((size_t)3072 * 1024 * 2);
  u16* wprojT  = (u16*)alloc((size_t)1024 * 1024 * 2);
  u16* wmlp1T  = (u16*)alloc((size_t)4096 * 1024 * 2);
  u16* wmlp2T  = (u16*)alloc((size_t)1024 * 4096 * 2);
  u16* xmod    = (u16*)alloc((size_t)8192 * 1024 * 2);   // reused as attention out y
  u16* qkv     = (u16*)alloc((size_t)8192 * 3072 * 2);   // front reused as x_mod2
  u16* vt      = (u16*)alloc((size_t)8 * 16 * 64 * 1024 * 2);
  float* x1    = (float*)alloc((size_t)8192 * 1024 * 4);
  u16* hbuf    = (u16*)alloc((size_t)8192 * 4096 * 2);
  u16* ybuf  = xmod;   // x_mod dead after qkv GEMM
  u16* xmod2 = qkv;    // qkv dead after attention

  adaln_part_k<<<dim3(24, 32), 256, 0, stream>>>(c, w_ada, apart);
  adaln_red_k<<<192, 256, 0, stream>>>(apart, b_ada, cmod);
  tcast_k<<<dim3(3072 / 64, 1024 / 64), 256, 0, stream>>>(w_qkv,  wqkvT,  1024, 3072,
                                                          1024, 2048, 1.0f / 64.0f);
  tcast_k<<<dim3(1024 / 64, 1024 / 64), 256, 0, stream>>>(w_proj, wprojT, 1024, 1024, 0, 0, 1.f);
  tcast_k<<<dim3(4096 / 64, 1024 / 64), 256, 0, stream>>>(w_mlp1, wmlp1T, 1024, 4096, 0, 0, 1.f);
  tcast_k<<<dim3(1024 / 64, 4096 / 64), 256, 0, stream>>>(w_mlp2, wmlp2T, 4096, 1024, 0, 0, 1.f);
  lnmod_k<<<8192, 256, 0, stream>>>(x, cmod, 0, 1024, xmod);
  gemm8_k<0><<<dim3(3072 / 256, 8192 / 256), 512, 0, stream>>>(
      xmod, wqkvT, 3072, 1024, nullptr, nullptr, nullptr, qkv);
  tv_k<<<dim3(128, 16), 256, 0, stream>>>(qkv, vt);
  attn_k<<<dim3(16, 16, 8), 256, 0, stream>>>(qkv, vt, ybuf);
  gemm8_k<2><<<dim3(1024 / 256, 8192 / 256), 512, 0, stream>>>(
      ybuf, wprojT, 1024, 1024, b_proj, x, cmod + 2048, x1);
  lnmod_k<<<8192, 256, 0, stream>>>(x1, cmod, 3072, 4096, xmod2);
  gemm8_k<1><<<dim3(4096 / 256, 8192 / 256), 512, 0, stream>>>(
      xmod2, wmlp1T, 4096, 1024, b_mlp1, nullptr, nullptr, hbuf);
  gemm8_k<2><<<dim3(1024 / 256, 8192 / 256), 512, 0, stream>>>(
      hbuf, wmlp2T, 1024, 4096, b_mlp2, x1, cmod + 5120, out);
}

// Round 8
// 409.432 us; speedup vs baseline: 1.1212x; 1.0676x over previous
//
#include <hip/hip_runtime.h>
#include <stdint.h>

typedef unsigned short u16;
using bf16x8 = __attribute__((ext_vector_type(8))) __bf16;
using f32x4  = __attribute__((ext_vector_type(4))) float;

#define MFMA16(a,b,c) __builtin_amdgcn_mfma_f32_16x16x32_bf16((a),(b),(c),0,0,0)

__device__ __forceinline__ u16 f2bf(float f) {
  union { float f; uint32_t u; } v; v.f = f;
  uint32_t r = v.u + 0x7FFFu + ((v.u >> 16) & 1u);
  return (u16)(r >> 16);
}

// async global->LDS, 16B per lane; lds ptr must be wave-uniform (HW: base + lane*16)
__device__ __forceinline__ void gload_lds16(const void* g, void* l) {
  typedef const __attribute__((address_space(1))) void* gp_t;
  typedef __attribute__((address_space(3))) void* lp_t;
  __builtin_amdgcn_global_load_lds((gp_t)(uintptr_t)g,
                                   (lp_t)(uint32_t)(uintptr_t)l, 16, 0, 0);
}

// ---------------- adaLN stage 1 ----------------
__global__ __launch_bounds__(256)
void adaln_part_k(const float* __restrict__ c, const float* __restrict__ w,
                  float* __restrict__ partial) {
  const int jb = blockIdx.x, ks = blockIdx.y;
  const int j = jb * 256 + threadIdx.x;
  __shared__ float sil[8][32];
  {
    int b = threadIdx.x >> 5, kk = threadIdx.x & 31;
    float v = c[b * 1024 + ks * 32 + kk];
    sil[b][kk] = v / (1.f + __expf(-v));
  }
  __syncthreads();
  float acc[8] = {0,0,0,0,0,0,0,0};
#pragma unroll 8
  for (int kk = 0; kk < 32; ++kk) {
    float wv = w[(size_t)(ks * 32 + kk) * 6144 + j];
#pragma unroll
    for (int b = 0; b < 8; ++b) acc[b] += sil[b][kk] * wv;
  }
#pragma unroll
  for (int b = 0; b < 8; ++b)
    partial[((size_t)ks * 8 + b) * 6144 + j] = acc[b];
}

// ---------------- adaLN stage 2 ----------------
__global__ __launch_bounds__(256)
void adaln_red_k(const float* __restrict__ partial, const float* __restrict__ bias,
                 float* __restrict__ cmod) {
  int g = blockIdx.x * 256 + threadIdx.x;
  int j = g % 6144;
  float s = bias[j];
#pragma unroll 8
  for (int ks = 0; ks < 32; ++ks)
    s += partial[(size_t)ks * 8 * 6144 + g];
  cmod[g] = s;
}

// ------- weight cast+transpose: fp32 [K][N] -> bf16 [N][K]; cols [lo,hi) scaled -------
__global__ __launch_bounds__(256)
void tcast_k(const float* __restrict__ in, u16* __restrict__ out, int K, int N,
             int lo, int hi, float scale) {
  __shared__ u16 t[64][65];
  int n0 = blockIdx.x * 64, k0 = blockIdx.y * 64;
#pragma unroll
  for (int i = 0; i < 16; ++i) {
    int idx = i * 256 + threadIdx.x;
    int r = idx >> 6, cc = idx & 63;
    float v = in[(size_t)(k0 + r) * N + n0 + cc];
    int n = n0 + cc;
    if (n >= lo && n < hi) v *= scale;
    t[r][cc] = f2bf(v);
  }
  __syncthreads();
#pragma unroll
  for (int i = 0; i < 16; ++i) {
    int idx = i * 256 + threadIdx.x;
    int r = idx >> 6, cc = idx & 63;
    out[(size_t)(n0 + r) * K + k0 + cc] = t[cc][r];
  }
}

// ---------------- LN + modulate -> bf16 ----------------
__global__ __launch_bounds__(256)
void lnmod_k(const float* __restrict__ x, const float* __restrict__ cmod,
             int shift_off, int scale_off, u16* __restrict__ out) {
  int row = blockIdx.x;
  int b = row >> 10;
  const float4* xr = (const float4*)(x + (size_t)row * 1024);
  float4 v = xr[threadIdx.x];
  float s = v.x + v.y + v.z + v.w;
  float sq = v.x * v.x + v.y * v.y + v.z * v.z + v.w * v.w;
#pragma unroll
  for (int m = 32; m >= 1; m >>= 1) {
    s  += __shfl_xor(s, m);
    sq += __shfl_xor(sq, m);
  }
  __shared__ float ss[4], ssq[4];
  int wave = threadIdx.x >> 6, lane = threadIdx.x & 63;
  if (lane == 0) { ss[wave] = s; ssq[wave] = sq; }
  __syncthreads();
  s  = ss[0] + ss[1] + ss[2] + ss[3];
  sq = ssq[0] + ssq[1] + ssq[2] + ssq[3];
  float mean = s * (1.f / 1024.f);
  float var  = sq * (1.f / 1024.f) - mean * mean;
  float rstd = rsqrtf(var + 1e-6f);
  int col = threadIdx.x * 4;
  const float* sh = cmod + (size_t)b * 6144 + shift_off + col;
  const float* sc = cmod + (size_t)b * 6144 + scale_off + col;
  float xv[4] = {v.x, v.y, v.z, v.w};
  union { u16 o[4]; uint64_t u; } pk;
#pragma unroll
  for (int j = 0; j < 4; ++j)
    pk.o[j] = f2bf((xv[j] - mean) * rstd * (1.f + sc[j]) + sh[j]);
  *(uint64_t*)(out + (size_t)row * 1024 + col) = pk.u;
}

// ---------------- transpose V section of qkv -> vt[b,h,ch,s] bf16 ----------------
__global__ __launch_bounds__(256)
void tv_k(const u16* __restrict__ qkv, u16* __restrict__ vt) {
  __shared__ u16 t[64][65];
  int r0 = blockIdx.x * 64;
  int h = blockIdx.y;
  int b = r0 >> 10;
  int s0 = r0 & 1023;
#pragma unroll
  for (int i = 0; i < 16; ++i) {
    int idx = i * 256 + threadIdx.x;
    int r = idx >> 6, cc = idx & 63;
    t[r][cc] = qkv[(size_t)(r0 + r) * 3072 + 2048 + h * 64 + cc];
  }
  __syncthreads();
#pragma unroll
  for (int i = 0; i < 16; ++i) {
    int idx = i * 256 + threadIdx.x;
    int ch = idx >> 6, scc = idx & 63;
    vt[((size_t)(b * 16 + h) * 64 + ch) * 1024 + s0 + scc] = t[scc][ch];
  }
}

// ==== GEMM v6: round-3 structure (128x128, BK=32, 2-buffer, 32KB LDS, ~2.5 blk/CU)
//      + 2-way-free chunk swizzle c^=((r>>1)&3)  (slot = 4(r&1)+c' covers all 8 -> free)
//      + XCD-aware bijective block swizzle (T1). ====
__device__ __forceinline__ float gelu_f(float x) {
  float z = 1.5957691216057308f * (x + 0.044715f * x * x * x);
  return x / (1.f + __expf(-z));
}

template <int EP>
__global__ __launch_bounds__(256)
void gemm_k(const u16* __restrict__ A, const u16* __restrict__ Bt,
            int N, int K,
            const float* __restrict__ bias, const float* __restrict__ resid,
            const float* __restrict__ gate, void* __restrict__ outp) {
  __shared__ __align__(16) u16 lds[2][2][128 * 32];
  // T1: bijective chunked XCD swizzle (all grids have nwg % 8 == 0)
  const int nwg = gridDim.x * gridDim.y;
  int bid = blockIdx.y * gridDim.x + blockIdx.x;
  int swz = (bid & 7) * (nwg >> 3) + (bid >> 3);
  const int bn = swz % gridDim.x, bm = swz / gridDim.x;
  const int tid = threadIdx.x;
  const int wave = tid >> 6, lane = tid & 63;
  const int l15 = lane & 15, lhi = lane >> 4;
  const int wr = wave >> 1, wc = wave & 1;
  f32x4 acc[4][4] = {};
  const int nkt = K >> 5;
  const size_t arow0 = (size_t)bm * 128;
  const size_t brow0 = (size_t)bn * 128;

  auto stage = [&](int buf, int kt) {
#pragma unroll
    for (int i = 0; i < 2; ++i) {
      int c = (i * 4 + wave) * 64 + lane;       // chunk id 0..511
      int row = c >> 2;
      int kc = (c & 3) ^ ((row >> 1) & 3);      // inverse swizzle on SOURCE (rule 21)
      gload_lds16(A  + (arow0 + row) * K + (size_t)kt * 32 + kc * 8,
                  &lds[buf][0][(i * 4 + wave) * 512]);
      gload_lds16(Bt + (brow0 + row) * K + (size_t)kt * 32 + kc * 8,
                  &lds[buf][1][(i * 4 + wave) * 512]);
    }
  };

  stage(0, 0);
  __syncthreads();
  for (int kt = 0; kt < nkt; ++kt) {
    int cur = kt & 1;
    if (kt + 1 < nkt) stage(cur ^ 1, kt + 1);
    bf16x8 af[4], bfr[4];
#pragma unroll
    for (int m = 0; m < 4; ++m) {
      int r = wr * 64 + m * 16 + l15;
      af[m] = *(const bf16x8*)&lds[cur][0][r * 32 + (lhi ^ ((r >> 1) & 3)) * 8];
    }
#pragma unroll
    for (int n = 0; n < 4; ++n) {
      int r = wc * 64 + n * 16 + l15;
      bfr[n] = *(const bf16x8*)&lds[cur][1][r * 32 + (lhi ^ ((r >> 1) & 3)) * 8];
    }
#pragma unroll
    for (int m = 0; m < 4; ++m)
#pragma unroll
      for (int n = 0; n < 4; ++n)
        acc[m][n] = MFMA16(af[m], bfr[n], acc[m][n]);
    __syncthreads();
  }

#pragma unroll
  for (int m = 0; m < 4; ++m) {
    int row = bm * 128 + wr * 64 + m * 16 + lhi * 4;
#pragma unroll
    for (int n = 0; n < 4; ++n) {
      int col = bn * 128 + wc * 64 + n * 16 + l15;
#pragma unroll
      for (int r = 0; r < 4; ++r) {
        int rr = row + r;
        float v = acc[m][n][r];
        if (EP == 0) {
          ((u16*)outp)[(size_t)rr * N + col] = f2bf(v);
        } else if (EP == 1) {
          ((u16*)outp)[(size_t)rr * N + col] = f2bf(gelu_f(v + bias[col]));
        } else {
          float t = v + bias[col];
          int b = rr >> 10;
          float res = resid[(size_t)rr * N + col];
          ((float*)outp)[(size_t)rr * N + col] = res + gate[(size_t)b * 6144 + col] * t;
        }
      }
    }
  }
}

// ---------------- flash attention: block = (q-tile 64, head, batch), T1-swizzled ----------------
__global__ __launch_bounds__(256)
void attn_k(const u16* __restrict__ qkv, const u16* __restrict__ vt,
            u16* __restrict__ y) {
  // T1: cluster the 16 qt-blocks of one (b,h) on one XCD (K/V L2 locality).
  // grid = 2048 = 8 chunks x 256; chunk x covers b = x, all (h, qt).
  int bid0 = blockIdx.x + 16 * (blockIdx.y + 16 * blockIdx.z);
  int swz = (bid0 & 7) * 256 + (bid0 >> 3);
  const int qt = swz & 15, h = (swz >> 4) & 15, b = swz >> 8;
  const int tid = threadIdx.x, wave = tid >> 6, lane = tid & 63;
  const int l15 = lane & 15, lhi = lane >> 4;
  __shared__ __align__(16) u16 Qs[64 * 64];
  __shared__ __align__(16) u16 Ks[2][64 * 64];
  __shared__ __align__(16) u16 Vs[2][64 * 64];
  __shared__ __align__(16) u16 Ps[64 * 64];
  const size_t qrow0 = (size_t)b * 1024 + qt * 64;
  const size_t krow0 = (size_t)b * 1024;
  const size_t vrow0 = (size_t)(b * 16 + h) * 64;

  auto stageQ = [&]() {
#pragma unroll
    for (int i = 0; i < 2; ++i) {
      int c = (i * 4 + wave) * 64 + lane;
      int r = c >> 3, j = (c & 7) ^ (c >> 3 & 7);
      gload_lds16(qkv + (qrow0 + r) * 3072 + 1024 + h * 64 + j * 8,
                  &Qs[(i * 4 + wave) * 512]);
    }
  };
  auto stageKV = [&](int buf, int kt) {
#pragma unroll
    for (int i = 0; i < 2; ++i) {
      int c = (i * 4 + wave) * 64 + lane;
      int r = c >> 3, j = (c & 7) ^ (c >> 3 & 7);
      gload_lds16(qkv + (krow0 + kt * 64 + r) * 3072 + h * 64 + j * 8,
                  &Ks[buf][(i * 4 + wave) * 512]);
      gload_lds16(vt + (vrow0 + r) * 1024 + kt * 64 + j * 8,
                  &Vs[buf][(i * 4 + wave) * 512]);
    }
  };
  auto ldb = [](const u16* base, int row, int cc) -> bf16x8 {
    return *(const bf16x8*)&base[row * 64 + ((cc ^ (row & 7)) << 3)];
  };

  stageQ();
  stageKV(0, 0);
  __syncthreads();
  bf16x8 qf[2];
  qf[0] = ldb(Qs, wave * 16 + l15, lhi);
  qf[1] = ldb(Qs, wave * 16 + l15, 4 + lhi);

  bf16x8 ones;
#pragma unroll
  for (int j = 0; j < 8; ++j) ones[j] = (__bf16)1.0f;

  float m_r[4];
  f32x4 o[5] = {};
#pragma unroll
  for (int r = 0; r < 4; ++r) m_r[r] = -3.0e38f;

  for (int kt = 0; kt < 16; ++kt) {
    int cur = kt & 1;
    if (kt < 15) stageKV(cur ^ 1, kt + 1);
    f32x4 sf[4] = {};
    __builtin_amdgcn_s_setprio(1);
#pragma unroll
    for (int n = 0; n < 4; ++n) {
      bf16x8 k0 = ldb(Ks[cur], n * 16 + l15, lhi);
      bf16x8 k1 = ldb(Ks[cur], n * 16 + l15, 4 + lhi);
      sf[n] = MFMA16(qf[0], k0, sf[n]);
      sf[n] = MFMA16(qf[1], k1, sf[n]);
    }
    __builtin_amdgcn_s_setprio(0);
#pragma unroll
    for (int r = 0; r < 4; ++r) {
      float mx = fmaxf(fmaxf(sf[0][r], sf[1][r]), fmaxf(sf[2][r], sf[3][r]));
      mx = fmaxf(mx, __shfl_xor(mx, 1));
      mx = fmaxf(mx, __shfl_xor(mx, 2));
      mx = fmaxf(mx, __shfl_xor(mx, 4));
      mx = fmaxf(mx, __shfl_xor(mx, 8));
      float mn = fmaxf(m_r[r], mx);
      float al = __expf(m_r[r] - mn);
      m_r[r] = mn;
      float p0 = __expf(sf[0][r] - mn);
      float p1 = __expf(sf[1][r] - mn);
      float p2 = __expf(sf[2][r] - mn);
      float p3 = __expf(sf[3][r] - mn);
      o[0][r] *= al; o[1][r] *= al; o[2][r] *= al; o[3][r] *= al; o[4][r] *= al;
      int row = wave * 16 + lhi * 4 + r;
      int rb = row * 64, sw = (row & 7) << 3;
      Ps[rb + (l15 ^ sw)]        = f2bf(p0);
      Ps[rb + ((l15 + 16) ^ sw)] = f2bf(p1);
      Ps[rb + ((l15 + 32) ^ sw)] = f2bf(p2);
      Ps[rb + ((l15 + 48) ^ sw)] = f2bf(p3);
    }
    bf16x8 pf0 = ldb(Ps, wave * 16 + l15, lhi);
    bf16x8 pf1 = ldb(Ps, wave * 16 + l15, 4 + lhi);
    __builtin_amdgcn_s_setprio(1);
#pragma unroll
    for (int n = 0; n < 4; ++n) {
      bf16x8 v0 = ldb(Vs[cur], n * 16 + l15, lhi);
      bf16x8 v1 = ldb(Vs[cur], n * 16 + l15, 4 + lhi);
      o[n] = MFMA16(pf0, v0, o[n]);
      o[n] = MFMA16(pf1, v1, o[n]);
    }
    o[4] = MFMA16(pf0, ones, o[4]);
    o[4] = MFMA16(pf1, ones, o[4]);
    __builtin_amdgcn_s_setprio(0);
    __syncthreads();
  }
#pragma unroll
  for (int r = 0; r < 4; ++r) {
    float inv = 1.0f / o[4][r];
    size_t yrow = (qrow0 + wave * 16 + lhi * 4 + r) * 1024 + h * 64 + l15;
    y[yrow]      = f2bf(o[0][r] * inv);
    y[yrow + 16] = f2bf(o[1][r] * inv);
    y[yrow + 32] = f2bf(o[2][r] * inv);
    y[yrow + 48] = f2bf(o[3][r] * inv);
  }
}

// ---------------- host ----------------
extern "C" void kernel_launch(void* const* d_in, const int* in_sizes, int n_in,
                              void* d_out, int out_size, void* d_ws, size_t ws_size,
                              hipStream_t stream) {
  const float* x      = (const float*)d_in[0];
  const float* c      = (const float*)d_in[1];
  const float* w_ada  = (const float*)d_in[2];
  const float* b_ada  = (const float*)d_in[3];
  const float* w_qkv  = (const float*)d_in[4];
  const float* w_proj = (const float*)d_in[5];
  const float* b_proj = (const float*)d_in[6];
  const float* w_mlp1 = (const float*)d_in[7];
  const float* b_mlp1 = (const float*)d_in[8];
  const float* w_mlp2 = (const float*)d_in[9];
  const float* b_mlp2 = (const float*)d_in[10];
  float* out = (float*)d_out;

  char* ws = (char*)d_ws;
  size_t off = 0;
  auto alloc = [&](size_t bytes) {
    void* p = ws + off;
    off += (bytes + 255) & ~(size_t)255;
    return p;
  };
  float* cmod  = (float*)alloc((size_t)8 * 6144 * 4);
  float* apart = (float*)alloc((size_t)32 * 8 * 6144 * 4);
  u16* wqkvT   = (u16*)alloc((size_t)3072 * 1024 * 2);
  u16* wprojT  = (u16*)alloc((size_t)1024 * 1024 * 2);
  u16* wmlp1T  = (u16*)alloc((size_t)4096 * 1024 * 2);
  u16* wmlp2T  = (u16*)alloc((size_t)1024 * 4096 * 2);
  u16* xmod    = (u16*)alloc((size_t)8192 * 1024 * 2);   // reused as attention out y
  u16* qkv     = (u16*)alloc((size_t)8192 * 3072 * 2);   // front reused as x_mod2
  u16* vt      = (u16*)alloc((size_t)8 * 16 * 64 * 1024 * 2);
  float* x1    = (float*)alloc((size_t)8192 * 1024 * 4);
  u16* hbuf    = (u16*)alloc((size_t)8192 * 4096 * 2);
  u16* ybuf  = xmod;   // x_mod dead after qkv GEMM
  u16* xmod2 = qkv;    // qkv dead after attention

  adaln_part_k<<<dim3(24, 32), 256, 0, stream>>>(c, w_ada, apart);
  adaln_red_k<<<192, 256, 0, stream>>>(apart, b_ada, cmod);
  tcast_k<<<dim3(3072 / 64, 1024 / 64), 256, 0, stream>>>(w_qkv,  wqkvT,  1024, 3072,
                                                          1024, 2048, 1.0f / 64.0f);
  tcast_k<<<dim3(1024 / 64, 1024 / 64), 256, 0, stream>>>(w_proj, wprojT, 1024, 1024, 0, 0, 1.f);
  tcast_k<<<dim3(4096 / 64, 1024 / 64), 256, 0, stream>>>(w_mlp1, wmlp1T, 1024, 4096, 0, 0, 1.f);
  tcast_k<<<dim3(1024 / 64, 4096 / 64), 256, 0, stream>>>(w_mlp2, wmlp2T, 4096, 1024, 0, 0, 1.f);
  lnmod_k<<<8192, 256, 0, stream>>>(x, cmod, 0, 1024, xmod);
  gemm_k<0><<<dim3(3072 / 128, 8192 / 128), 256, 0, stream>>>(
      xmod, wqkvT, 3072, 1024, nullptr, nullptr, nullptr, qkv);
  tv_k<<<dim3(128, 16), 256, 0, stream>>>(qkv, vt);
  attn_k<<<dim3(16, 16, 8), 256, 0, stream>>>(qkv, vt, ybuf);
  gemm_k<2><<<dim3(1024 / 128, 8192 / 128), 256, 0, stream>>>(
      ybuf, wprojT, 1024, 1024, b_proj, x, cmod + 2048, x1);
  lnmod_k<<<8192, 256, 0, stream>>>(x1, cmod, 3072, 4096, xmod2);
  gemm_k<1><<<dim3(4096 / 128, 8192 / 128), 256, 0, stream>>>(
      xmod2, wmlp1T, 4096, 1024, b_mlp1, nullptr, nullptr, hbuf);
  gemm_k<2><<<dim3(1024 / 128, 8192 / 128), 256, 0, stream>>>(
      hbuf, wmlp2T, 1024, 4096, b_mlp2, x1, cmod + 5120, out);
}